// Round 1
// baseline (3085.796 us; speedup 1.0000x reference)
//
#include <hip/hip_runtime.h>

// LSTM over T=512 steps, B=512, H=256. Strategy:
//  - 32 blocks x 512 threads (8 waves). Block b handles batches [16b, 16b+16).
//  - W_hh held in registers as fp16 MFMA B-fragments, persistent across all steps.
//    Wave w owns h-indices [32w,32w+32) -> gate cols {g*256 + 32w + x}, 128 cols/wave.
//  - h state round-trips through double-buffered LDS (fp16), 1 barrier/step.
//  - Output projection accumulated per-step into registers; reduced at the end.
//  - MFMA f32_16x16x32_f16: A[m=lane&15][k=quad*8+j], B[k=quad*8+j][n=lane&15],
//    D[m=quad*4+reg][n=lane&15]  (per verified gfx950 layouts).

typedef _Float16 half8 __attribute__((ext_vector_type(8)));
typedef float f32x4 __attribute__((ext_vector_type(4)));

constexpr int kT = 512;
constexpr int kBT = 16;     // batches per block
constexpr int kNW = 8;      // waves per block

__device__ __forceinline__ float fexp2(float x) { return __builtin_amdgcn_exp2f(x); }
__device__ __forceinline__ float frcp(float x) { return __builtin_amdgcn_rcpf(x); }
// sigmoid(x) = 1/(1+2^(-x*log2e)); inf-safe at both ends
__device__ __forceinline__ float sigm(float x) {
    return frcp(1.0f + fexp2(-1.44269504088896340736f * x));
}
// tanh(x) = 1 - 2/(1+2^(2x*log2e)); inf-safe at both ends
__device__ __forceinline__ float tanh_f(float x) {
    return 1.0f - 2.0f * frcp(1.0f + fexp2(2.88539008177792681472f * x));
}

__global__ __launch_bounds__(512, 2)
void lstm_persist(const float* __restrict__ ts,
                  const float* __restrict__ W_ih,
                  const float* __restrict__ W_hh,
                  const float* __restrict__ b_ih,
                  const float* __restrict__ b_hh,
                  const float* __restrict__ W_out,
                  const float* __restrict__ b_out,
                  float* __restrict__ out)
{
    __shared__ __align__(16) _Float16 h_lds[2][16][264]; // +8 pad breaks bank aliasing
    __shared__ float ts_lds[16][513];                    // +1 pad: quads hit distinct banks
    __shared__ float red[kNW][16];

    const int tid  = threadIdx.x;
    const int w    = tid >> 6;     // wave 0..7
    const int lane = tid & 63;
    const int l16  = lane & 15;
    const int quad = lane >> 4;
    const int b0   = blockIdx.x * kBT;

    // ---- stage ts tile [16][512] into LDS (coalesced) ----
    for (int i = tid; i < kBT * kT; i += 512) {
        int bb = i >> 9, tt = i & 511;
        ts_lds[bb][tt] = ts[(b0 + bb) * kT + tt];
    }
    // ---- zero h buffer 0 (h0 = 0) ----
    for (int i = tid; i < 16 * 264; i += 512) {
        h_lds[0][i / 264][i % 264] = (_Float16)0.0f;
    }

    // ---- load W_hh into registers as B-fragments; preload W_ih / bias per col ----
    half8 bw[8][8];          // [nt][kt] : 256 VGPRs of weights
    float wih[8], bias[8];
    #pragma unroll
    for (int nt = 0; nt < 8; ++nt) {
        int c = nt * 16 + l16;                       // wave-local col 0..127
        int r = (c >> 5) * 256 + w * 32 + (c & 31);  // global gate row (i,f,g,o order)
        wih[nt]  = W_ih[r];
        bias[nt] = b_ih[r] + b_hh[r];
        #pragma unroll
        for (int kt = 0; kt < 8; ++kt) {
            int k = kt * 32 + quad * 8;
            const float* src = W_hh + r * 256 + k;
            f32x4 lo = *reinterpret_cast<const f32x4*>(src);
            f32x4 hi = *reinterpret_cast<const f32x4*>(src + 4);
            half8 v;
            v[0] = (_Float16)lo[0]; v[1] = (_Float16)lo[1];
            v[2] = (_Float16)lo[2]; v[3] = (_Float16)lo[3];
            v[4] = (_Float16)hi[0]; v[5] = (_Float16)hi[1];
            v[6] = (_Float16)hi[2]; v[7] = (_Float16)hi[3];
            bw[nt][kt] = v;
        }
    }

    float cst[8];                 // c-state: [e][reg] = 2 h-cols x 4 batches per lane
    #pragma unroll
    for (int i = 0; i < 8; ++i) cst[i] = 0.0f;
    float out_acc[4] = {0.f, 0.f, 0.f, 0.f};

    __syncthreads();

    int p = 0;
    const int hbase = w * 32 + l16;  // this lane's h-index (e=0 half)
    for (int t = 0; t < kT; ++t) {
        // A fragments: h[batch = l16][k-slice]
        half8 a[8];
        #pragma unroll
        for (int kt = 0; kt < 8; ++kt) {
            a[kt] = *reinterpret_cast<const half8*>(&h_lds[p][l16][kt * 32 + quad * 8]);
        }
        // gates = h @ W_hh^T  (fp32 accumulate)
        f32x4 acc[8];
        #pragma unroll
        for (int nt = 0; nt < 8; ++nt) {
            f32x4 z = {0.f, 0.f, 0.f, 0.f};
            acc[nt] = z;
            #pragma unroll
            for (int kt = 0; kt < 8; ++kt) {
                acc[nt] = __builtin_amdgcn_mfma_f32_16x16x32_f16(a[kt], bw[nt][kt], acc[nt], 0, 0, 0);
            }
        }
        float tsv[4];
        #pragma unroll
        for (int r = 0; r < 4; ++r) tsv[r] = ts_lds[quad * 4 + r][t];
        float wo0 = W_out[t * 256 + hbase];
        float wo1 = W_out[t * 256 + hbase + 16];

        #pragma unroll
        for (int e = 0; e < 2; ++e) {
            float wo = e ? wo1 : wo0;
            #pragma unroll
            for (int r = 0; r < 4; ++r) {
                // i,f,g,o for (batch = quad*4+r, h = w*32 + l16 + 16e), all in this lane
                float gi = acc[0 + e][r] + tsv[r] * wih[0 + e] + bias[0 + e];
                float gf = acc[2 + e][r] + tsv[r] * wih[2 + e] + bias[2 + e];
                float gg = acc[4 + e][r] + tsv[r] * wih[4 + e] + bias[4 + e];
                float go = acc[6 + e][r] + tsv[r] * wih[6 + e] + bias[6 + e];
                float I = sigm(gi), F = sigm(gf), Gg = tanh_f(gg), O = sigm(go);
                float c_new = F * cst[e * 4 + r] + I * Gg;
                cst[e * 4 + r] = c_new;
                float hv = O * tanh_f(c_new);
                out_acc[r] += hv * wo;
                h_lds[p ^ 1][quad * 4 + r][hbase + 16 * e] = (_Float16)hv;
            }
        }
        __syncthreads();
        p ^= 1;
    }

    // ---- reduce out_acc: over 16 l16 lanes (different h), then over waves ----
    #pragma unroll
    for (int r = 0; r < 4; ++r) {
        float v = out_acc[r];
        v += __shfl_xor(v, 1, 64);
        v += __shfl_xor(v, 2, 64);
        v += __shfl_xor(v, 4, 64);
        v += __shfl_xor(v, 8, 64);
        out_acc[r] = v;
    }
    if (l16 == 0) {
        #pragma unroll
        for (int r = 0; r < 4; ++r) red[w][quad * 4 + r] = out_acc[r];
    }
    __syncthreads();
    if (tid < kBT) {
        float s = b_out[0];
        #pragma unroll
        for (int ww = 0; ww < kNW; ++ww) s += red[ww][tid];
        out[b0 + tid] = s;
    }
}

extern "C" void kernel_launch(void* const* d_in, const int* in_sizes, int n_in,
                              void* d_out, int out_size, void* d_ws, size_t ws_size,
                              hipStream_t stream) {
    const float* ts    = (const float*)d_in[0];
    const float* W_ih  = (const float*)d_in[1];
    const float* W_hh  = (const float*)d_in[2];
    const float* b_ih  = (const float*)d_in[3];
    const float* b_hh  = (const float*)d_in[4];
    const float* W_out = (const float*)d_in[5];
    const float* b_out = (const float*)d_in[6];
    lstm_persist<<<32, 512, 0, stream>>>(ts, W_ih, W_hh, b_ih, b_hh, W_out, b_out, (float*)d_out);
}

// Round 3
// 2895.099 us; speedup vs baseline: 1.0659x; 1.0659x over previous
//
#include <hip/hip_runtime.h>

// LSTM B=512, T=512, H=256, streaming-weight design.
//  - prep_weights: W_hh fp32 -> fp16 MFMA B-fragments in d_ws, prescaled by
//    -log2e (i,f,o) or +2log2e (g) so sigmoid/tanh need no pre-multiply.
//  - lstm_main: 32 blocks x 512 thr (8 waves), block owns 16 batches.
//    Wave w owns h-cols [32w,32w+32); lane l16 owns h = 32w + 2*l16 + {0,1}.
//    Weight tiles streamed from L2 each step, double-buffered (64 VGPRs),
//    overlapping MFMA. h state double-buffered in LDS, 1 barrier/step.
//  - MFMA f32_16x16x32_f16: A[m=l16][k=quad*8+j], B[k=quad*8+j][n=l16],
//    D[m=quad*4+r][n=l16].

typedef _Float16 half8 __attribute__((ext_vector_type(8)));
typedef _Float16 half2t __attribute__((ext_vector_type(2)));
typedef float f32x4 __attribute__((ext_vector_type(4)));
typedef float f32x2 __attribute__((ext_vector_type(2)));

constexpr int kT = 512;
constexpr int kBT = 16;     // batches per block
constexpr int kNW = 8;      // waves per block
constexpr int kHP = 272;    // h_lds row stride (halves): 544B -> 2-way-max banks, 16B aligned
constexpr float kLog2e = 1.44269504088896340736f;

// frag element index: (((w*8+nt)*8+kt)*64+lane)*8+j ; nt = g*2+e
// value = W_hh[g*256 + w*32 + 2*(lane&15) + e][kt*32 + (lane>>4)*8 + j] * s
__global__ void prep_weights(const float* __restrict__ W_hh, _Float16* __restrict__ ws)
{
    int idx = blockIdx.x * blockDim.x + threadIdx.x;  // 0..32767, one half8 each
    int lane = idx & 63;
    int frag = idx >> 6;
    int kt = frag & 7;
    int nt = (frag >> 3) & 7;
    int w  = frag >> 6;
    int g = nt >> 1, e = nt & 1;
    int r = g * 256 + w * 32 + 2 * (lane & 15) + e;
    int k = kt * 32 + (lane >> 4) * 8;
    float s = (g == 2) ? 2.0f * kLog2e : -kLog2e;
    const float* src = W_hh + r * 256 + k;
    half8 v;
    #pragma unroll
    for (int j = 0; j < 8; ++j) v[j] = (_Float16)(src[j] * s);
    reinterpret_cast<half8*>(ws)[idx] = v;
}

__global__ __launch_bounds__(512, 2)
void lstm_main(const float* __restrict__ ts,
               const float* __restrict__ W_ih,
               const float* __restrict__ b_ih,
               const float* __restrict__ b_hh,
               const float* __restrict__ W_out,
               const float* __restrict__ b_out,
               const _Float16* __restrict__ wfrag,
               float* __restrict__ out)
{
    __shared__ __align__(16) _Float16 h_lds[2][16][kHP];
    __shared__ float ts_lds[16][513];
    __shared__ float red[kNW][16];

    const int tid  = threadIdx.x;
    const int w    = tid >> 6;
    const int lane = tid & 63;
    const int l16  = lane & 15;
    const int quad = lane >> 4;
    const int b0   = blockIdx.x * kBT;

    // stage ts tile [16][512] (coalesced)
    for (int i = tid; i < kBT * kT; i += 512) {
        int bb = i >> 9, tt = i & 511;
        ts_lds[bb][tt] = ts[(b0 + bb) * kT + tt];
    }
    // zero h buffer 0
    for (int i = tid; i < 16 * kHP; i += 512)
        h_lds[0][i / kHP][i % kHP] = (_Float16)0.0f;

    // per-column scalar params, prescaled (column n=l16 of tile nt -> this lane)
    float wih[8], bias[8];
    #pragma unroll
    for (int nt = 0; nt < 8; ++nt) {
        int g = nt >> 1, e = nt & 1;
        int r = g * 256 + w * 32 + 2 * l16 + e;
        float s = (g == 2) ? 2.0f * kLog2e : -kLog2e;
        wih[nt]  = W_ih[r] * s;
        bias[nt] = (b_ih[r] + b_hh[r]) * s;
    }

    // per-lane weight-fragment pointer: frag (nt,kt) at wp[nt*512 + kt*64]
    const half8* wp = reinterpret_cast<const half8*>(wfrag) + w * 4096 + lane;

    float cst[8] = {0, 0, 0, 0, 0, 0, 0, 0};
    float oacc[4] = {0.f, 0.f, 0.f, 0.f};

    __syncthreads();

    int p = 0;
    const int hb = w * 32 + 2 * l16;   // this lane's first h-index
    for (int t = 0; t < kT; ++t) {
        // A fragments: h[batch=l16][k-slice]
        half8 a[8];
        #pragma unroll
        for (int kt = 0; kt < 8; ++kt)
            a[kt] = *reinterpret_cast<const half8*>(&h_lds[p][l16][kt * 32 + quad * 8]);

        f32x2 wo = *reinterpret_cast<const f32x2*>(W_out + t * 256 + hb);
        float tsv[4];
        #pragma unroll
        for (int r = 0; r < 4; ++r) tsv[r] = ts_lds[quad * 4 + r][t];

        // gates = h @ W_hh'^T, streaming B-tiles from L2 with double buffer
        f32x4 acc[8];
        half8 wb[2][8];
        #pragma unroll
        for (int kt = 0; kt < 8; ++kt) wb[0][kt] = wp[kt * 64];
        #pragma unroll
        for (int nt = 0; nt < 8; ++nt) {
            if (nt < 7) {
                #pragma unroll
                for (int kt = 0; kt < 8; ++kt)
                    wb[(nt + 1) & 1][kt] = wp[(nt + 1) * 512 + kt * 64];
            }
            f32x4 z = {0.f, 0.f, 0.f, 0.f};
            acc[nt] = z;
            #pragma unroll
            for (int kt = 0; kt < 8; ++kt)
                acc[nt] = __builtin_amdgcn_mfma_f32_16x16x32_f16(a[kt], wb[nt & 1][kt], acc[nt], 0, 0, 0);
        }

        // nonlinearity: lane handles (batch=quad*4+r, h=hb+e), gates prescaled
        #pragma unroll
        for (int r = 0; r < 4; ++r) {
            float hv[2];
            #pragma unroll
            for (int e = 0; e < 2; ++e) {
                float gi = acc[0 + e][r] + (tsv[r] * wih[0 + e] + bias[0 + e]);
                float gf = acc[2 + e][r] + (tsv[r] * wih[2 + e] + bias[2 + e]);
                float gg = acc[4 + e][r] + (tsv[r] * wih[4 + e] + bias[4 + e]);
                float go = acc[6 + e][r] + (tsv[r] * wih[6 + e] + bias[6 + e]);
                float I = __builtin_amdgcn_rcpf(1.0f + __builtin_amdgcn_exp2f(gi));
                float F = __builtin_amdgcn_rcpf(1.0f + __builtin_amdgcn_exp2f(gf));
                float G = 1.0f - 2.0f * __builtin_amdgcn_rcpf(1.0f + __builtin_amdgcn_exp2f(gg));
                float O = __builtin_amdgcn_rcpf(1.0f + __builtin_amdgcn_exp2f(go));
                float c = F * cst[e * 4 + r] + I * G;
                cst[e * 4 + r] = c;
                float tc = 1.0f - 2.0f * __builtin_amdgcn_rcpf(
                               1.0f + __builtin_amdgcn_exp2f(2.0f * kLog2e * c));
                hv[e] = O * tc;
                oacc[r] += hv[e] * wo[e];
            }
            half2t h2;
            h2[0] = (_Float16)hv[0];
            h2[1] = (_Float16)hv[1];
            *reinterpret_cast<half2t*>(&h_lds[p ^ 1][quad * 4 + r][hb]) = h2;
        }
        __syncthreads();
        p ^= 1;
    }

    // reduce oacc over the 16 l16 lanes (different h), then over waves
    #pragma unroll
    for (int r = 0; r < 4; ++r) {
        float v = oacc[r];
        v += __shfl_xor(v, 1, 64);
        v += __shfl_xor(v, 2, 64);
        v += __shfl_xor(v, 4, 64);
        v += __shfl_xor(v, 8, 64);
        oacc[r] = v;
    }
    if (l16 == 0) {
        #pragma unroll
        for (int r = 0; r < 4; ++r) red[w][quad * 4 + r] = oacc[r];
    }
    __syncthreads();
    if (tid < kBT) {
        float s = b_out[0];
        #pragma unroll
        for (int ww = 0; ww < kNW; ++ww) s += red[ww][tid];
        out[b0 + tid] = s;
    }
}

extern "C" void kernel_launch(void* const* d_in, const int* in_sizes, int n_in,
                              void* d_out, int out_size, void* d_ws, size_t ws_size,
                              hipStream_t stream) {
    const float* ts    = (const float*)d_in[0];
    const float* W_ih  = (const float*)d_in[1];
    const float* W_hh  = (const float*)d_in[2];
    const float* b_ih  = (const float*)d_in[3];
    const float* b_hh  = (const float*)d_in[4];
    const float* W_out = (const float*)d_in[5];
    const float* b_out = (const float*)d_in[6];
    _Float16* wfrag = (_Float16*)d_ws;   // 512 KB of fragments

    prep_weights<<<128, 256, 0, stream>>>(W_hh, wfrag);
    lstm_main<<<32, 512, 0, stream>>>(ts, W_ih, b_ih, b_hh, W_out, b_out,
                                      wfrag, (float*)d_out);
}

// Round 4
// 1681.459 us; speedup vs baseline: 1.8352x; 1.7218x over previous
//
#include <hip/hip_runtime.h>

// LSTM B=512, T=512, H=256. Round 4: three-tier weight residency.
// Per-CU L1 return path is ~64 B/cyc -> streaming all 512 KB of W_hh per step
// (round 3) floors at ~8K cyc/step. Fix: per wave, of the 8 K-slices (kt):
//   kt 0..3 -> persistent registers (128 VGPRs/lane, 256 KB/CU)
//   kt 4..5 -> LDS, staged once     (128 KB/CU, ds_read_b128 per step)
//   kt 6..7 -> streamed from L2     (128 KB/CU/step through the 64 B/cyc straw)
// 32 blocks x 512 thr (8 waves); block owns 16 batches; wave w owns gate-cols
// via nt=g*2+e tiles so all 4 gates of (b,h) land in one lane. h double-buffered
// in LDS, 1 barrier/step. Weights prescaled by -log2e (i,f,o) / +2log2e (g).
// MFMA f32_16x16x32_f16: A[m=l16][k=quad*8+j], B[k=quad*8+j][n=l16], D[m=quad*4+r][n=l16].

typedef _Float16 half8 __attribute__((ext_vector_type(8)));
typedef _Float16 half2t __attribute__((ext_vector_type(2)));
typedef float f32x4 __attribute__((ext_vector_type(4)));
typedef float f32x2 __attribute__((ext_vector_type(2)));

constexpr int kT = 512;
constexpr int kBT = 16;
constexpr int kNW = 8;
constexpr int kHP = 272;   // h_lds row stride (halves)
constexpr float kLog2e = 1.44269504088896340736f;

// ws layout, half8 units (16 B each):
//   REG  [0,16384):     f = idx>>6 = w*32 + nt*4 + kt          (kt 0..3)
//   LDSW [16384,24576): f = w*16 + nt*2 + j                    (kt = 4+j)
//   STRM [24576,32768): f = w*16 + nt*2 + j                    (kt = 6+j)
// element: r = g*256 + w*32 + 2*(lane&15) + e (nt=g*2+e), k = kt*32 + (lane>>4)*8 + jj
__global__ void prep_weights(const float* __restrict__ W_hh, _Float16* __restrict__ ws)
{
    int gid = blockIdx.x * blockDim.x + threadIdx.x;  // 0..32767
    int lane = gid & 63;
    int w, nt, kt;
    if (gid < 16384) {
        int f = gid >> 6;
        kt = f & 3; nt = (f >> 2) & 7; w = f >> 5;
    } else if (gid < 24576) {
        int f = (gid - 16384) >> 6;
        kt = 4 + (f & 1); nt = (f >> 1) & 7; w = f >> 4;
    } else {
        int f = (gid - 24576) >> 6;
        kt = 6 + (f & 1); nt = (f >> 1) & 7; w = f >> 4;
    }
    int g = nt >> 1, e = nt & 1;
    int r = g * 256 + w * 32 + 2 * (lane & 15) + e;
    int k = kt * 32 + (lane >> 4) * 8;
    float s = (g == 2) ? 2.0f * kLog2e : -kLog2e;
    const float* src = W_hh + r * 256 + k;
    half8 v;
    #pragma unroll
    for (int j = 0; j < 8; ++j) v[j] = (_Float16)(src[j] * s);
    reinterpret_cast<half8*>(ws)[gid] = v;
}

__global__ __launch_bounds__(512, 2)
void lstm_main(const float* __restrict__ ts,
               const float* __restrict__ W_ih,
               const float* __restrict__ b_ih,
               const float* __restrict__ b_hh,
               const float* __restrict__ W_out,
               const float* __restrict__ b_out,
               const _Float16* __restrict__ wfrag,
               float* __restrict__ out)
{
    __shared__ __align__(16) _Float16 wlds[65536];      // 128 KB: kt 4..5 weights
    __shared__ __align__(16) _Float16 h_lds[2][16][kHP]; // 17 KB
    __shared__ float red[kNW][16];

    const int tid  = threadIdx.x;
    const int w    = tid >> 6;
    const int lane = tid & 63;
    const int l16  = lane & 15;
    const int quad = lane >> 4;
    const int b0   = blockIdx.x * kBT;

    const half8* wf8 = reinterpret_cast<const half8*>(wfrag);
    half8* wlds8 = reinterpret_cast<half8*>(wlds);

    // stage LDS-tier weights (one-time, coalesced)
    for (int i = tid; i < 8192; i += 512) wlds8[i] = wf8[16384 + i];
    // zero h buffer 0
    for (int i = tid; i < 16 * kHP; i += 512)
        h_lds[0][i / kHP][i % kHP] = (_Float16)0.0f;

    // register-tier weights: 128 VGPRs/lane
    half8 wreg[8][4];
    #pragma unroll
    for (int nt = 0; nt < 8; ++nt)
        #pragma unroll
        for (int kt = 0; kt < 4; ++kt)
            wreg[nt][kt] = wf8[(w * 32 + nt * 4 + kt) * 64 + lane];

    // per-column scalars (prescaled)
    float wih[8], bias[8];
    #pragma unroll
    for (int nt = 0; nt < 8; ++nt) {
        int g = nt >> 1, e = nt & 1;
        int r = g * 256 + w * 32 + 2 * l16 + e;
        float s = (g == 2) ? 2.0f * kLog2e : -kLog2e;
        wih[nt]  = W_ih[r] * s;
        bias[nt] = (b_ih[r] + b_hh[r]) * s;
    }

    // stream-tier per-lane pointer: frag (nt,j) at sp[(nt*2+j)*64]
    const half8* sp = wf8 + 24576 + w * 1024 + lane;

    float cst[8] = {0, 0, 0, 0, 0, 0, 0, 0};
    float oacc[4] = {0.f, 0.f, 0.f, 0.f};

    __syncthreads();

    int p = 0;
    const int hb = w * 32 + 2 * l16;
    const int ldsbase = w * 16 * 64;   // wave's wlds region, half8 units

    for (int t = 0; t < kT; ++t) {
        // A fragments from LDS
        half8 a[8];
        #pragma unroll
        for (int kt = 0; kt < 8; ++kt)
            a[kt] = *reinterpret_cast<const half8*>(&h_lds[p][l16][kt * 32 + quad * 8]);

        // per-step small loads (issued early, consumed late)
        f32x2 wo = *reinterpret_cast<const f32x2*>(W_out + t * 256 + hb);
        float tsv[4];
        #pragma unroll
        for (int r = 0; r < 4; ++r) tsv[r] = ts[(b0 + quad * 4 + r) * kT + t];

        // stream prefetch: depth-3 rotation over nt tiles (24 VGPRs)
        half8 sb[3][2];
        #pragma unroll
        for (int n = 0; n < 3; ++n) {
            sb[n][0] = sp[(n * 2 + 0) * 64];
            sb[n][1] = sp[(n * 2 + 1) * 64];
        }

        f32x4 acc[8];
        #pragma unroll
        for (int nt = 0; nt < 8; ++nt) {
            // LDS-tier fragments for this nt
            half8 lw0 = wlds8[ldsbase + (nt * 2 + 0) * 64 + lane];
            half8 lw1 = wlds8[ldsbase + (nt * 2 + 1) * 64 + lane];
            f32x4 z = {0.f, 0.f, 0.f, 0.f};
            acc[nt] = z;
            #pragma unroll
            for (int kt = 0; kt < 4; ++kt)
                acc[nt] = __builtin_amdgcn_mfma_f32_16x16x32_f16(a[kt], wreg[nt][kt], acc[nt], 0, 0, 0);
            acc[nt] = __builtin_amdgcn_mfma_f32_16x16x32_f16(a[4], lw0, acc[nt], 0, 0, 0);
            acc[nt] = __builtin_amdgcn_mfma_f32_16x16x32_f16(a[5], lw1, acc[nt], 0, 0, 0);
            acc[nt] = __builtin_amdgcn_mfma_f32_16x16x32_f16(a[6], sb[nt % 3][0], acc[nt], 0, 0, 0);
            acc[nt] = __builtin_amdgcn_mfma_f32_16x16x32_f16(a[7], sb[nt % 3][1], acc[nt], 0, 0, 0);
            if (nt < 5) {   // refill consumed slot for nt+3
                sb[nt % 3][0] = sp[((nt + 3) * 2 + 0) * 64];
                sb[nt % 3][1] = sp[((nt + 3) * 2 + 1) * 64];
            }
        }

        // nonlinearity: lane owns (batch=quad*4+r, h=hb+e); gates prescaled
        #pragma unroll
        for (int r = 0; r < 4; ++r) {
            float hv[2];
            #pragma unroll
            for (int e = 0; e < 2; ++e) {
                float gi = acc[0 + e][r] + (tsv[r] * wih[0 + e] + bias[0 + e]);
                float gf = acc[2 + e][r] + (tsv[r] * wih[2 + e] + bias[2 + e]);
                float gg = acc[4 + e][r] + (tsv[r] * wih[4 + e] + bias[4 + e]);
                float go = acc[6 + e][r] + (tsv[r] * wih[6 + e] + bias[6 + e]);
                float I = __builtin_amdgcn_rcpf(1.0f + __builtin_amdgcn_exp2f(gi));
                float F = __builtin_amdgcn_rcpf(1.0f + __builtin_amdgcn_exp2f(gf));
                float G = 1.0f - 2.0f * __builtin_amdgcn_rcpf(1.0f + __builtin_amdgcn_exp2f(gg));
                float O = __builtin_amdgcn_rcpf(1.0f + __builtin_amdgcn_exp2f(go));
                float c = F * cst[e * 4 + r] + I * G;
                cst[e * 4 + r] = c;
                float tc = 1.0f - 2.0f * __builtin_amdgcn_rcpf(
                               1.0f + __builtin_amdgcn_exp2f(2.0f * kLog2e * c));
                hv[e] = O * tc;
                oacc[r] += hv[e] * wo[e];
            }
            half2t h2;
            h2[0] = (_Float16)hv[0];
            h2[1] = (_Float16)hv[1];
            *reinterpret_cast<half2t*>(&h_lds[p ^ 1][quad * 4 + r][hb]) = h2;
        }
        __syncthreads();
        p ^= 1;
    }

    // reduce oacc over the 16 l16 lanes (different h), then over waves
    #pragma unroll
    for (int r = 0; r < 4; ++r) {
        float v = oacc[r];
        v += __shfl_xor(v, 1, 64);
        v += __shfl_xor(v, 2, 64);
        v += __shfl_xor(v, 4, 64);
        v += __shfl_xor(v, 8, 64);
        oacc[r] = v;
    }
    if (l16 == 0) {
        #pragma unroll
        for (int r = 0; r < 4; ++r) red[w][quad * 4 + r] = oacc[r];
    }
    __syncthreads();
    if (tid < kBT) {
        float s = b_out[0];
        #pragma unroll
        for (int ww = 0; ww < kNW; ++ww) s += red[ww][tid];
        out[b0 + tid] = s;
    }
}

extern "C" void kernel_launch(void* const* d_in, const int* in_sizes, int n_in,
                              void* d_out, int out_size, void* d_ws, size_t ws_size,
                              hipStream_t stream) {
    const float* ts    = (const float*)d_in[0];
    const float* W_ih  = (const float*)d_in[1];
    const float* W_hh  = (const float*)d_in[2];
    const float* b_ih  = (const float*)d_in[3];
    const float* b_hh  = (const float*)d_in[4];
    const float* W_out = (const float*)d_in[5];
    const float* b_out = (const float*)d_in[6];
    _Float16* wfrag = (_Float16*)d_ws;   // 512 KB of fragments

    prep_weights<<<128, 256, 0, stream>>>(W_hh, wfrag);
    lstm_main<<<32, 512, 0, stream>>>(ts, W_ih, b_ih, b_hh, W_out, b_out,
                                      wfrag, (float*)d_out);
}